// Round 5
// baseline (246.823 us; speedup 1.0000x reference)
//
#include <hip/hip_runtime.h>

#define DIM 32
#define RCR 128             // receivers per region -> nc = 782 at N=100K
#define NCMAX 1024          // max regions supported
#define PBLK 128            // place blocks (one cell per (region, place-block))
#define SUBCAP 48           // cap per cell; mean 16 (+8 sigma)
#define REGSZ (PBLK * SUBCAP)   // 6144 slots per region
#define CAPC 2816           // rsort LDS stage cap; region mean 2048, +17 sigma
#define QROWS 128           // rows per GEMM block

// ---------------- f16 / bf16 <-> fp32 helpers ------------------------------
__device__ __forceinline__ float b2f(ushort h) {
    union { float f; unsigned u; } u; u.u = ((unsigned)h) << 16; return u.f;
}
__device__ __forceinline__ float h2f(ushort u) {
    _Float16 h; __builtin_memcpy(&h, &u, 2); return (float)h;
}
__device__ __forceinline__ ushort f2h(float f) {
    _Float16 h = (_Float16)f; ushort u; __builtin_memcpy(&u, &h, 2); return u;
}
__device__ __forceinline__ int clampN(int v, int n) {
    return v < 0 ? 0 : (v >= n ? n - 1 : v);
}
__device__ __forceinline__ int load_idx(const int* __restrict__ idx, size_t pos,
                                        int mode, int n) {
    int v = mode ? idx[2 * pos] : idx[pos];
    return clampN(v, n);
}
__device__ __forceinline__ float load_f(const void* p, size_t i, int bf) {
    return bf ? b2f(((const ushort*)p)[i]) : ((const float*)p)[i];
}

// ---------------------------------------------------------------------------
// K1a (place): 128 blocks x 1024 threads (was 256 -> 4x per-block
// parallelism; R4 measured the fused version's tail at 65-70 us with
// Occupancy 24%). Block-private cells -> dense single-XCD write lines
// (R2 measured the cross-XCD alternative at 120 MB HBM writes).
// ---------------------------------------------------------------------------
__global__ void __launch_bounds__(1024)
place_kernel(const int* __restrict__ idx, int N, int E, int nc,
             unsigned* __restrict__ bedges, int* __restrict__ hcnt) {
    __shared__ int sh[NCMAX];
    __shared__ int sMode;

    const int tid = threadIdx.x;
    if (tid < 64) {
        unsigned long long mm = __ballot(idx[2 * tid + 1] != 0);
        if (tid == 0) sMode = (mm == 0ULL);
    }
    for (int i = tid; i < nc; i += 1024) sh[i] = 0;
    __syncthreads();
    const int mode = sMode;

    const int pb = blockIdx.x;
    const int per = (E + PBLK - 1) / PBLK;
    const int e0 = pb * per;
    const int e1 = min(e0 + per, E);
    for (int e = e0 + tid; e < e1; e += 1024) {
        const int r = load_idx(idx, (size_t)E + e, mode, N);
        const int s = load_idx(idx, (size_t)e, mode, N);
        const int reg = r >> 7;               // r / RCR
        const int rl  = r & (RCR - 1);
        const int p = atomicAdd(&sh[reg], 1);
        if (p < SUBCAP)
            bedges[(size_t)reg * REGSZ + pb * SUBCAP + p] =
                (unsigned)s | ((unsigned)rl << 17);
    }
    __syncthreads();
    for (int i = tid; i < nc; i += 1024)
        hcnt[i * PBLK + pb] = min(sh[i], SUBCAP);
}

// ---------------------------------------------------------------------------
// K1b (QKV GEMM): 782 blocks x 256 thr, 128 rows/block, 4 rows/thread
// (W fragments reused across rows: 33 LDS b128/thread vs 104 in the R4
// 1-row layout). f16 out, Q pre-scaled by 1/sqrt(32).
// sx stride 36 floats: 16B-aligned rows, +4-bank shift/row -> conflict-free.
// ---------------------------------------------------------------------------
__global__ void __launch_bounds__(256)
gemm_kernel(const void* __restrict__ x_, const void* __restrict__ Wq_,
            const void* __restrict__ Wk_, const void* __restrict__ Wv_,
            int N, ushort* __restrict__ Q, ushort* __restrict__ KV) {
    __shared__ float sW[3][DIM * DIM];
    __shared__ float sx[QROWS][36];
    __shared__ int sBf;

    const int tid = threadIdx.x;
    if (tid < 64) {
        int e = (((const ushort*)x_)[2 * tid] >> 7) & 0xFF;
        unsigned long long bb = __ballot(e >= 100 && e <= 135);
        if (tid == 0) sBf = (__popcll(bb) >= 56);
    }
    __syncthreads();
    const int bf = sBf;

    for (int i = tid; i < DIM * DIM; i += 256) {
        sW[0][i] = load_f(Wq_, i, bf);
        sW[1][i] = load_f(Wk_, i, bf);
        sW[2][i] = load_f(Wv_, i, bf);
    }
    const int base = blockIdx.x * QROWS;
    for (int i = tid; i < QROWS * 8; i += 256) {   // 8 float4-chunks per row
        const int r  = i >> 3;
        const int c4 = (i & 7) << 2;
        const int row = base + r;
        float4 v; v.x = v.y = v.z = v.w = 0.f;
        if (row < N) {
            if (!bf) {
                v = *(const float4*)((const float*)x_ + (size_t)row * DIM + c4);
            } else {
                const ushort4 u =
                    *(const ushort4*)((const ushort*)x_ + (size_t)row * DIM + c4);
                v.x = b2f(u.x); v.y = b2f(u.y); v.z = b2f(u.z); v.w = b2f(u.w);
            }
        }
        *(float4*)&sx[r][c4] = v;
    }
    __syncthreads();

    const int lr = tid >> 3;          // 0..31; thread rows: lr + 32*rr
    const int d4 = (tid & 7) << 2;    // 4-col group
    float aq[4][4] = {}, ak[4][4] = {}, av[4][4] = {};
#pragma unroll
    for (int k0 = 0; k0 < DIM; k0 += 4) {
        float xv[4][4];
#pragma unroll
        for (int rr = 0; rr < 4; ++rr) {
            const float4 t = *(const float4*)&sx[lr + 32 * rr][k0];
            xv[rr][0] = t.x; xv[rr][1] = t.y; xv[rr][2] = t.z; xv[rr][3] = t.w;
        }
#pragma unroll
        for (int kk = 0; kk < 4; ++kk) {
            const float4 wq = *(const float4*)&sW[0][(k0 + kk) * DIM + d4];
            const float4 wk = *(const float4*)&sW[1][(k0 + kk) * DIM + d4];
            const float4 wv = *(const float4*)&sW[2][(k0 + kk) * DIM + d4];
#pragma unroll
            for (int rr = 0; rr < 4; ++rr) {
                const float xvv = xv[rr][kk];
                aq[rr][0] = fmaf(xvv, wq.x, aq[rr][0]);
                aq[rr][1] = fmaf(xvv, wq.y, aq[rr][1]);
                aq[rr][2] = fmaf(xvv, wq.z, aq[rr][2]);
                aq[rr][3] = fmaf(xvv, wq.w, aq[rr][3]);
                ak[rr][0] = fmaf(xvv, wk.x, ak[rr][0]);
                ak[rr][1] = fmaf(xvv, wk.y, ak[rr][1]);
                ak[rr][2] = fmaf(xvv, wk.z, ak[rr][2]);
                ak[rr][3] = fmaf(xvv, wk.w, ak[rr][3]);
                av[rr][0] = fmaf(xvv, wv.x, av[rr][0]);
                av[rr][1] = fmaf(xvv, wv.y, av[rr][1]);
                av[rr][2] = fmaf(xvv, wv.z, av[rr][2]);
                av[rr][3] = fmaf(xvv, wv.w, av[rr][3]);
            }
        }
    }
    const float sc = 0.17677669529663687f;   // 1/sqrt(32), pre-scale Q
#pragma unroll
    for (int rr = 0; rr < 4; ++rr) {
        const int row = base + lr + 32 * rr;
        if (row < N) {
            ushort4 t;
            t.x = f2h(aq[rr][0] * sc); t.y = f2h(aq[rr][1] * sc);
            t.z = f2h(aq[rr][2] * sc); t.w = f2h(aq[rr][3] * sc);
            *(ushort4*)&Q[(size_t)row * DIM + d4] = t;
            t.x = f2h(ak[rr][0]); t.y = f2h(ak[rr][1]);
            t.z = f2h(ak[rr][2]); t.w = f2h(ak[rr][3]);
            *(ushort4*)&KV[(size_t)row * 64 + d4] = t;
            t.x = f2h(av[rr][0]); t.y = f2h(av[rr][1]);
            t.z = f2h(av[rr][2]); t.w = f2h(av[rr][3]);
            *(ushort4*)&KV[(size_t)row * 64 + 32 + d4] = t;
        }
    }
}

// ---------------------------------------------------------------------------
// K2 (rsort): one 256-thread block per region of RCR=128 receivers.
// R4-identical algorithm; the staging loop now has a compile-time trip
// count + unroll 4 so multiple bedges loads are in flight per thread.
// ---------------------------------------------------------------------------
__global__ void __launch_bounds__(256)
rsort_kernel(unsigned* __restrict__ bedges, const int* __restrict__ hcnt,
             int* __restrict__ rbase, int* __restrict__ rcount, int N) {
    __shared__ unsigned eL[CAPC];     // 11.3 KB
    __shared__ int cnt[RCR];
    __shared__ int fills[PBLK];
    __shared__ int cbase[PBLK];
    __shared__ int wsum[4];

    const int tid = threadIdx.x;
    const int c = blockIdx.x;
    const size_t s0 = (size_t)c * REGSZ;
    const int lane = tid & 63, w = tid >> 6;

    if (tid < RCR) cnt[tid] = 0;
    if (tid < PBLK) fills[tid] = hcnt[c * PBLK + tid];
    __syncthreads();

    // exclusive prefix over fills[0..127] -> cbase (2 waves, shfl scan)
    int fv = 0, fx = 0;
    if (tid < PBLK) {
        fv = fills[tid]; fx = fv;
#pragma unroll
        for (int o = 1; o < 64; o <<= 1) {
            int t = __shfl_up(fx, o); if (lane >= o) fx += t;
        }
        if (lane == 63) wsum[w] = fx;
    }
    __syncthreads();
    if (tid == 0) { int t0 = wsum[0]; wsum[0] = 0; wsum[1] = t0; }
    __syncthreads();
    if (tid < PBLK) cbase[tid] = fx - fv + wsum[w];
    __syncthreads();
    const int nTot = cbase[PBLK - 1] + fills[PBLK - 1];

    // atomic-free compact staging + r_local histogram (4 loads in flight)
#pragma unroll 4
    for (int it = 0; it < REGSZ / 256; ++it) {
        const int i    = it * 256 + tid;
        const int cell = i / SUBCAP;
        const int q    = i - cell * SUBCAP;
        if (q < fills[cell]) {
            const int p = cbase[cell] + q;
            if (p < CAPC) {
                const unsigned e = bedges[s0 + i];
                eL[p] = e;
                atomicAdd(&cnt[(e >> 17) & (RCR - 1)], 1);
            }
        }
    }
    __syncthreads();

    // exclusive prefix over cnt[0..127] -> per-receiver CSR
    const int v = (tid < RCR) ? cnt[tid] : 0;
    int x = v;
    if (tid < RCR) {
#pragma unroll
        for (int o = 1; o < 64; o <<= 1) {
            int t = __shfl_up(x, o); if (lane >= o) x += t;
        }
        if (lane == 63) wsum[w] = x;
    }
    __syncthreads();
    if (tid == 0) { int t0 = wsum[0]; wsum[0] = 0; wsum[1] = t0; }
    __syncthreads();
    int excl = 0;
    if (tid < RCR) {
        excl = x - v + wsum[w];
        rbase[c * RCR + tid]  = (int)s0 + excl;
        rcount[c * RCR + tid] = v;
    }
    __syncthreads();
    if (tid < RCR) cnt[tid] = (int)s0 + excl;
    __syncthreads();

    const int m = min(nTot, CAPC);
    for (int i = tid; i < m; i += 256) {
        const unsigned e = eL[i];
        const int p = atomicAdd(&cnt[(e >> 17) & (RCR - 1)], 1);
        bedges[p] = e & 0x1FFFF;
    }
}

// ---------------------------------------------------------------------------
// K3 (agg): byte-identical to the proven 64 us agg (control: expect ~64 us,
// FETCH ~88 MB, VALUBusy ~46%). Wave-per-receiver-PAIR over sorted CSR,
// register accumulation + shfl reduce, fused normalize + @Wo + residual.
// ---------------------------------------------------------------------------
__global__ void __launch_bounds__(256)
agg_kernel(const ushort* __restrict__ Q, const ushort* __restrict__ KV,
           const unsigned* __restrict__ bedges, const int* __restrict__ rbase,
           const int* __restrict__ rcount, const void* __restrict__ x_,
           const void* __restrict__ Wo_, int N, float* __restrict__ out) {
    __shared__ float sWo[DIM * DIM];
    __shared__ float accS[32][DIM + 1];
    __shared__ float Zs[32];
    __shared__ unsigned sQ[32 * 16];
    __shared__ int sBf;

    const int tid = threadIdx.x;
    if (tid < 64) {
        int e = (((const ushort*)x_)[2 * tid] >> 7) & 0xFF;
        unsigned long long bb = __ballot(e >= 100 && e <= 135);
        if (tid == 0) sBf = (__popcll(bb) >= 56);
    }
    const int r0 = blockIdx.x * 32;
    const int nr = min(32, N - r0);
    __syncthreads();
    const int bf = sBf;

    for (int i = tid; i < DIM * DIM; i += 256) sWo[i] = load_f(Wo_, i, bf);
    for (int i = tid; i < nr * 16; i += 256)
        sQ[i] = ((const unsigned*)(Q + (size_t)r0 * DIM))[i];
    __syncthreads();

    const int w    = tid >> 6;
    const int lane = tid & 63;
    const int i8   = lane >> 3;   // edge sub-slot 0..7
    const int j    = lane & 7;    // channel group 0..7

    for (int t = w; t < nr; t += 8) {
        const int rlA = t;
        const int rlB = t + 4;
        const bool hasB = (rlB < nr);

        const int degA = rcount[r0 + rlA];
        const int o0A  = rbase[r0 + rlA];
        const int degB = hasB ? rcount[r0 + rlB] : 0;
        const int o0B  = hasB ? rbase[r0 + rlB] : o0A;

        const ushort4 qa = *(const ushort4*)((const ushort*)sQ + rlA * DIM + j * 4);
        const ushort4 qb = *(const ushort4*)((const ushort*)sQ + (rlB & 31) * DIM + j * 4);
        const float qA0 = h2f(qa.x), qA1 = h2f(qa.y), qA2 = h2f(qa.z), qA3 = h2f(qa.w);
        const float qB0 = h2f(qb.x), qB1 = h2f(qb.y), qB2 = h2f(qb.z), qB3 = h2f(qb.w);

        float axA = 0.f, ayA = 0.f, azA = 0.f, awA = 0.f, zsA = 0.f;
        float axB = 0.f, ayB = 0.f, azB = 0.f, awB = 0.f, zsB = 0.f;

        const int chA = (degA + 7) >> 3;
        const int chB = (degB + 7) >> 3;
        const int cmax = max(chA, chB);
        const int dmA = max(degA - 1, 0);
        const int dmB = max(degB - 1, 0);

        for (int cc = 0; cc < cmax; cc += 2) {
            const int c0 = cc * 8 + i8;
            const int c1 = c0 + 8;
            const bool okA0 = (c0 < degA), okA1 = (c1 < degA);
            const bool okB0 = (c0 < degB), okB1 = (c1 < degB);

            const int sA0 = (int)bedges[o0A + (okA0 ? c0 : dmA)];
            const int sA1 = (int)bedges[o0A + (okA1 ? c1 : dmA)];
            const int sB0 = (int)bedges[o0B + (okB0 ? c0 : dmB)];
            const int sB1 = (int)bedges[o0B + (okB1 ? c1 : dmB)];

            const ushort* pA0 = KV + (size_t)sA0 * 64;
            const ushort* pA1 = KV + (size_t)sA1 * 64;
            const ushort* pB0 = KV + (size_t)sB0 * 64;
            const ushort* pB1 = KV + (size_t)sB1 * 64;

            // issue all 8 loads before any consumption
            const ushort4 khA0 = *(const ushort4*)(pA0 + j * 4);
            const ushort4 vhA0 = *(const ushort4*)(pA0 + 32 + j * 4);
            const ushort4 khA1 = *(const ushort4*)(pA1 + j * 4);
            const ushort4 vhA1 = *(const ushort4*)(pA1 + 32 + j * 4);
            const ushort4 khB0 = *(const ushort4*)(pB0 + j * 4);
            const ushort4 vhB0 = *(const ushort4*)(pB0 + 32 + j * 4);
            const ushort4 khB1 = *(const ushort4*)(pB1 + j * 4);
            const ushort4 vhB1 = *(const ushort4*)(pB1 + 32 + j * 4);

            float pA = h2f(khA0.x) * qA0;
            float pAx = h2f(khA1.x) * qA0;
            float pB = h2f(khB0.x) * qB0;
            float pBx = h2f(khB1.x) * qB0;
            pA  = fmaf(h2f(khA0.y), qA1, pA);   pAx = fmaf(h2f(khA1.y), qA1, pAx);
            pB  = fmaf(h2f(khB0.y), qB1, pB);   pBx = fmaf(h2f(khB1.y), qB1, pBx);
            pA  = fmaf(h2f(khA0.z), qA2, pA);   pAx = fmaf(h2f(khA1.z), qA2, pAx);
            pB  = fmaf(h2f(khB0.z), qB2, pB);   pBx = fmaf(h2f(khB1.z), qB2, pBx);
            pA  = fmaf(h2f(khA0.w), qA3, pA);   pAx = fmaf(h2f(khA1.w), qA3, pAx);
            pB  = fmaf(h2f(khB0.w), qB3, pB);   pBx = fmaf(h2f(khB1.w), qB3, pBx);

            pA  += __shfl_xor(pA, 1);   pAx += __shfl_xor(pAx, 1);
            pB  += __shfl_xor(pB, 1);   pBx += __shfl_xor(pBx, 1);
            pA  += __shfl_xor(pA, 2);   pAx += __shfl_xor(pAx, 2);
            pB  += __shfl_xor(pB, 2);   pBx += __shfl_xor(pBx, 2);
            pA  += __shfl_xor(pA, 4);   pAx += __shfl_xor(pAx, 4);
            pB  += __shfl_xor(pB, 4);   pBx += __shfl_xor(pBx, 4);

            pA  = fminf(fmaxf(pA,  -60.f), 60.f);
            pAx = fminf(fmaxf(pAx, -60.f), 60.f);
            pB  = fminf(fmaxf(pB,  -60.f), 60.f);
            pBx = fminf(fmaxf(pBx, -60.f), 60.f);
            const float aA0 = okA0 ? __expf(pA)  : 0.f;
            const float aA1 = okA1 ? __expf(pAx) : 0.f;
            const float aB0 = okB0 ? __expf(pB)  : 0.f;
            const float aB1 = okB1 ? __expf(pBx) : 0.f;

            axA = fmaf(h2f(vhA0.x), aA0, axA);  axA = fmaf(h2f(vhA1.x), aA1, axA);
            ayA = fmaf(h2f(vhA0.y), aA0, ayA);  ayA = fmaf(h2f(vhA1.y), aA1, ayA);
            azA = fmaf(h2f(vhA0.z), aA0, azA);  azA = fmaf(h2f(vhA1.z), aA1, azA);
            awA = fmaf(h2f(vhA0.w), aA0, awA);  awA = fmaf(h2f(vhA1.w), aA1, awA);
            zsA += aA0 + aA1;

            axB = fmaf(h2f(vhB0.x), aB0, axB);  axB = fmaf(h2f(vhB1.x), aB1, axB);
            ayB = fmaf(h2f(vhB0.y), aB0, ayB);  ayB = fmaf(h2f(vhB1.y), aB1, ayB);
            azB = fmaf(h2f(vhB0.z), aB0, azB);  azB = fmaf(h2f(vhB1.z), aB1, azB);
            awB = fmaf(h2f(vhB0.w), aB0, awB);  awB = fmaf(h2f(vhB1.w), aB1, awB);
            zsB += aB0 + aB1;
        }

#pragma unroll
        for (int o = 8; o < 64; o <<= 1) {
            axA += __shfl_xor(axA, o); ayA += __shfl_xor(ayA, o);
            azA += __shfl_xor(azA, o); awA += __shfl_xor(awA, o);
            zsA += __shfl_xor(zsA, o);
            axB += __shfl_xor(axB, o); ayB += __shfl_xor(ayB, o);
            azB += __shfl_xor(azB, o); awB += __shfl_xor(awB, o);
            zsB += __shfl_xor(zsB, o);
        }
        if (i8 == 0) {
            float* arA = accS[rlA];
            arA[j * 4 + 0] = axA; arA[j * 4 + 1] = ayA;
            arA[j * 4 + 2] = azA; arA[j * 4 + 3] = awA;
            if (j == 0) Zs[rlA] = zsA;
            if (hasB) {
                float* arB = accS[rlB];
                arB[j * 4 + 0] = axB; arB[j * 4 + 1] = ayB;
                arB[j * 4 + 2] = azB; arB[j * 4 + 3] = awB;
                if (j == 0) Zs[rlB] = zsB;
            }
        }
    }
    __syncthreads();

    const int lr = tid >> 5;
    const int d  = tid & 31;
#pragma unroll
    for (int it = 0; it < 4; ++it) {
        const int rl = it * 8 + lr;
        if (rl < nr) {
            const float inv = 1.f / (Zs[rl] + 1e-6f);
            float o = 0.f;
#pragma unroll
            for (int k = 0; k < DIM; ++k) o += accS[rl][k] * sWo[k * DIM + d];
            const size_t oi = (size_t)(r0 + rl) * DIM + d;
            out[oi] = load_f(x_, oi, bf) + inv * o;
        }
    }
}

// ---------------------------------------------------------------------------
extern "C" void kernel_launch(void* const* d_in, const int* in_sizes, int n_in,
                              void* d_out, int out_size, void* d_ws, size_t ws_size,
                              hipStream_t stream) {
    const void* x   = d_in[0];
    const int*  idx = (const int*)d_in[1];
    const void* Wq  = d_in[2];
    const void* Wk  = d_in[3];
    const void* Wv  = d_in[4];
    const void* Wo  = d_in[5];
    float* out = (float*)d_out;           // fp32 reference output

    const int N = in_sizes[0] / DIM;      // 100000
    const int E = in_sizes[1] / 2;        // 1600000
    const int nc = (N + RCR - 1) / RCR;   // 782 regions
    const size_t N32 = (size_t)N * DIM;

    // Workspace (~39.6 MB): Q f16 | KV f16 | bedges cells | hcnt | rbase | rcount
    ushort*   Q      = (ushort*)d_ws;
    ushort*   KV     = Q + N32;                              // N * 64 halves
    unsigned* bedges = (unsigned*)(KV + (size_t)N * 64);     // nc * REGSZ
    int*      hcnt   = (int*)(bedges + (size_t)nc * REGSZ);  // nc * PBLK
    int*      rbase  = hcnt + (size_t)nc * PBLK;             // nc * RCR
    int*      rcount = rbase + (size_t)nc * RCR;             // nc * RCR

    place_kernel<<<PBLK, 1024, 0, stream>>>(idx, N, E, nc, bedges, hcnt);

    gemm_kernel<<<(N + QROWS - 1) / QROWS, 256, 0, stream>>>(
        x, Wq, Wk, Wv, N, Q, KV);

    rsort_kernel<<<nc, 256, 0, stream>>>(bedges, hcnt, rbase, rcount, N);

    agg_kernel<<<(N + 31) / 32, 256, 0, stream>>>(Q, KV, bedges, rbase,
                                                  rcount, x, Wo, N, out);
}

// Round 6
// 219.255 us; speedup vs baseline: 1.1257x; 1.1257x over previous
//
#include <hip/hip_runtime.h>

#define DIM 32
#define RCR 128             // receivers per region -> nc = 782 at N=100K
#define NCMAX 1024          // max regions supported
#define PBLK 128            // place blocks (one cell per (region, place-block))
#define SUBCAP 48           // cap per cell; mean 16 (+8 sigma)
#define REGSZ (PBLK * SUBCAP)   // 6144 slots per region
#define CAPC 2816           // per-region staged-edge cap; mean 2048, +17 sigma

// ---------------- f16 / bf16 <-> fp32 helpers ------------------------------
__device__ __forceinline__ float b2f(ushort h) {
    union { float f; unsigned u; } u; u.u = ((unsigned)h) << 16; return u.f;
}
__device__ __forceinline__ float h2f(ushort u) {
    _Float16 h; __builtin_memcpy(&h, &u, 2); return (float)h;
}
__device__ __forceinline__ ushort f2h(float f) {
    _Float16 h = (_Float16)f; ushort u; __builtin_memcpy(&u, &h, 2); return u;
}
__device__ __forceinline__ int clampN(int v, int n) {
    return v < 0 ? 0 : (v >= n ? n - 1 : v);
}
__device__ __forceinline__ int load_idx(const int* __restrict__ idx, size_t pos,
                                        int mode, int n) {
    int v = mode ? idx[2 * pos] : idx[pos];
    return clampN(v, n);
}
__device__ __forceinline__ float load_f(const void* p, size_t i, int bf) {
    return bf ? b2f(((const ushort*)p)[i]) : ((const float*)p)[i];
}

// GEMM smem and place histogram share the block's LDS (union).
union K1Smem {
    struct { float sW[3][DIM * DIM]; float sx[32][36]; } g;   // 16.6 KB
    struct { int h[NCMAX]; } place;                           //  4 KB
};

// ---------------------------------------------------------------------------
// K1: byte-identical to R4 (measured 66-70 us -- CONTROL this round).
// blocks [0,PBLK) = cell-structured place (block-private cells -> dense
// single-XCD write lines). blocks [PBLK,..) = QKV GEMM, 32 rows/block,
// 1 row/thread (VGPR 48 measured; the 4-row variant spilled at VGPR 256).
// ---------------------------------------------------------------------------
__global__ void __launch_bounds__(256)
qkv_place_kernel(const void* __restrict__ x_, const int* __restrict__ idx,
                 const void* __restrict__ Wq_, const void* __restrict__ Wk_,
                 const void* __restrict__ Wv_, int N, int E, int nc,
                 ushort* __restrict__ Q, ushort* __restrict__ KV,
                 unsigned* __restrict__ bedges, int* __restrict__ hcnt) {
    __shared__ K1Smem sm;
    __shared__ int sBf, sMode;

    const int tid = threadIdx.x;
    if (tid < 64) {
        int e = (((const ushort*)x_)[2 * tid] >> 7) & 0xFF;
        unsigned long long bb = __ballot(e >= 100 && e <= 135);
        unsigned long long mm = __ballot(idx[2 * tid + 1] != 0);
        if (tid == 0) { sBf = (__popcll(bb) >= 56); sMode = (mm == 0ULL); }
    }
    __syncthreads();
    const int bf = sBf, mode = sMode;

    if (blockIdx.x < PBLK) {
        // ---- place: append edge (s | r_local<<17) into cell (region, pb) ----
        const int pb = blockIdx.x;
        for (int i = tid; i < nc; i += 256) sm.place.h[i] = 0;
        __syncthreads();
        const int per = (E + PBLK - 1) / PBLK;
        const int e0 = pb * per;
        const int e1 = min(e0 + per, E);
        for (int e = e0 + tid; e < e1; e += 256) {
            const int r = load_idx(idx, (size_t)E + e, mode, N);
            const int s = load_idx(idx, (size_t)e, mode, N);
            const int reg = r >> 7;               // r / RCR
            const int rl  = r & (RCR - 1);
            const int p = atomicAdd(&sm.place.h[reg], 1);
            if (p < SUBCAP)
                bedges[(size_t)reg * REGSZ + pb * SUBCAP + p] =
                    (unsigned)s | ((unsigned)rl << 17);
        }
        __syncthreads();
        for (int i = tid; i < nc; i += 256)
            hcnt[i * PBLK + pb] = min(sm.place.h[i], SUBCAP);
        return;
    }

    // ---- QKV GEMM: 32 rows/block, thread = (row, 4 contiguous cols) ----
    for (int i = tid; i < DIM * DIM; i += 256) {
        sm.g.sW[0][i] = load_f(Wq_, i, bf);
        sm.g.sW[1][i] = load_f(Wk_, i, bf);
        sm.g.sW[2][i] = load_f(Wv_, i, bf);
    }
    const int base = (blockIdx.x - PBLK) * 32;
    for (int i = tid; i < 32 * 8; i += 256) {      // 8 float4-chunks per row
        const int r  = i >> 3;
        const int c4 = (i & 7) << 2;
        const int row = base + r;
        float4 v; v.x = v.y = v.z = v.w = 0.f;
        if (row < N) {
            if (!bf) {
                v = *(const float4*)((const float*)x_ + (size_t)row * DIM + c4);
            } else {
                const ushort4 u =
                    *(const ushort4*)((const ushort*)x_ + (size_t)row * DIM + c4);
                v.x = b2f(u.x); v.y = b2f(u.y); v.z = b2f(u.z); v.w = b2f(u.w);
            }
        }
        *(float4*)&sm.g.sx[r][c4] = v;
    }
    __syncthreads();

    const int lr  = tid >> 3;          // row 0..31
    const int d4  = (tid & 7) << 2;    // 4-col group
    const int row = base + lr;
    if (row >= N) return;

    float aq[4] = {0.f, 0.f, 0.f, 0.f};
    float ak[4] = {0.f, 0.f, 0.f, 0.f};
    float av[4] = {0.f, 0.f, 0.f, 0.f};
#pragma unroll
    for (int k0 = 0; k0 < DIM; k0 += 4) {
        const float4 xq = *(const float4*)&sm.g.sx[lr][k0];
        const float xs[4] = {xq.x, xq.y, xq.z, xq.w};
#pragma unroll
        for (int kk = 0; kk < 4; ++kk) {
            const float xv = xs[kk];
            const float4 wq = *(const float4*)&sm.g.sW[0][(k0 + kk) * DIM + d4];
            const float4 wk = *(const float4*)&sm.g.sW[1][(k0 + kk) * DIM + d4];
            const float4 wv = *(const float4*)&sm.g.sW[2][(k0 + kk) * DIM + d4];
            aq[0] = fmaf(xv, wq.x, aq[0]); aq[1] = fmaf(xv, wq.y, aq[1]);
            aq[2] = fmaf(xv, wq.z, aq[2]); aq[3] = fmaf(xv, wq.w, aq[3]);
            ak[0] = fmaf(xv, wk.x, ak[0]); ak[1] = fmaf(xv, wk.y, ak[1]);
            ak[2] = fmaf(xv, wk.z, ak[2]); ak[3] = fmaf(xv, wk.w, ak[3]);
            av[0] = fmaf(xv, wv.x, av[0]); av[1] = fmaf(xv, wv.y, av[1]);
            av[2] = fmaf(xv, wv.z, av[2]); av[3] = fmaf(xv, wv.w, av[3]);
        }
    }
    const float sc = 0.17677669529663687f;   // 1/sqrt(32), pre-scale Q
    ushort4 t;
    t.x = f2h(aq[0] * sc); t.y = f2h(aq[1] * sc);
    t.z = f2h(aq[2] * sc); t.w = f2h(aq[3] * sc);
    *(ushort4*)&Q[(size_t)row * DIM + d4] = t;
    t.x = f2h(ak[0]); t.y = f2h(ak[1]); t.z = f2h(ak[2]); t.w = f2h(ak[3]);
    *(ushort4*)&KV[(size_t)row * 64 + d4] = t;
    t.x = f2h(av[0]); t.y = f2h(av[1]); t.z = f2h(av[2]); t.w = f2h(av[3]);
    *(ushort4*)&KV[(size_t)row * 64 + 32 + d4] = t;
}

// ---------------------------------------------------------------------------
// K2 (sortagg): rsort FUSED into agg. One 256-thread block per region of
// RCR=128 receivers. Phase 1 builds the per-receiver sorted edge list IN LDS
// (2-pass over the region's cells: histogram, prefix, scatter) -- never
// written back to global. Phase 2 is the PROVEN register-accumulating agg
// (identical math: 8 lanes/edge, shfl reduce, clamp +-60, __expf, fused
// normalize + @Wo + residual), reading edge indices from LDS.
// Standalone rsort was ~55-60 us with nothing to hide behind; here its
// latency chains overlap with co-resident blocks' KV-gather stalls
// (agg VALUBusy was 46% -> half the issue slots were idle).
// ---------------------------------------------------------------------------
__global__ void __launch_bounds__(256)
sortagg_kernel(const ushort* __restrict__ Q, const ushort* __restrict__ KV,
               const unsigned* __restrict__ bedges, const int* __restrict__ hcnt,
               const void* __restrict__ x_, const void* __restrict__ Wo_,
               int N, float* __restrict__ out) {
    __shared__ unsigned sortedL[CAPC];                 // 11.3 KB
    __shared__ __align__(16) ushort sQ[RCR * DIM];     //  8 KB
    __shared__ float accS[RCR][DIM + 1];               // 16.9 KB (acc + Z)
    __shared__ float sWo[DIM * DIM];                   //  4 KB
    __shared__ int fills[PBLK];
    __shared__ int cbase[PBLK];
    __shared__ int cnt[RCR];       // histogram, then scatter cursor
    __shared__ int rb[RCR];
    __shared__ int rc[RCR];
    __shared__ int wsum[2];
    __shared__ int sBf;

    const int tid = threadIdx.x;
    const int c   = blockIdx.x;
    const int r0  = c * RCR;
    const int nr  = min(RCR, N - r0);
    const size_t s0 = (size_t)c * REGSZ;
    const int lane = tid & 63, w = tid >> 6;

    if (tid < 64) {
        int e = (((const ushort*)x_)[2 * tid] >> 7) & 0xFF;
        unsigned long long bb = __ballot(e >= 100 && e <= 135);
        if (tid == 0) sBf = (__popcll(bb) >= 56);
    }
    if (tid < RCR) cnt[tid] = 0;
    if (tid < PBLK) fills[tid] = hcnt[c * PBLK + tid];
    for (int i = tid; i < CAPC; i += 256) sortedL[i] = 0;
    for (int i = tid; i < nr * 16; i += 256)
        ((unsigned*)sQ)[i] = ((const unsigned*)(Q + (size_t)r0 * DIM))[i];
    for (int i = tid; i < DIM * DIM; i += 256) sWo[i] = load_f(Wo_, i, sBf);
    __syncthreads();
    const int bf = sBf;

    // ---- exclusive prefix over fills[0..127] -> cbase (2-wave shfl scan) ----
    int fv = 0, fx = 0;
    if (tid < PBLK) {
        fv = fills[tid]; fx = fv;
#pragma unroll
        for (int o = 1; o < 64; o <<= 1) {
            int t = __shfl_up(fx, o); if (lane >= o) fx += t;
        }
        if (lane == 63) wsum[w] = fx;
    }
    __syncthreads();
    if (tid == 0) { int t0 = wsum[0]; wsum[0] = 0; wsum[1] = t0; }
    __syncthreads();
    if (tid < PBLK) cbase[tid] = fx - fv + wsum[w];
    __syncthreads();

    // ---- pass 1: r_local histogram over valid cell slots ----
    for (int it = 0; it < REGSZ / 256; ++it) {
        const int i    = it * 256 + tid;
        const int cell = i / SUBCAP;
        const int q    = i - cell * SUBCAP;
        if (q < fills[cell]) {
            const unsigned e = bedges[s0 + i];
            atomicAdd(&cnt[(e >> 17) & (RCR - 1)], 1);
        }
    }
    __syncthreads();

    // ---- exclusive prefix over cnt[0..127] -> per-receiver LDS CSR ----
    const int v = (tid < RCR) ? cnt[tid] : 0;
    int x = v;
    if (tid < RCR) {
#pragma unroll
        for (int o = 1; o < 64; o <<= 1) {
            int t = __shfl_up(x, o); if (lane >= o) x += t;
        }
        if (lane == 63) wsum[w] = x;
    }
    __syncthreads();
    if (tid == 0) { int t0 = wsum[0]; wsum[0] = 0; wsum[1] = t0; }
    __syncthreads();
    if (tid < RCR) {
        const int excl = x - v + wsum[w];
        rb[tid] = excl;
        rc[tid] = v;
        cnt[tid] = excl;          // scatter cursor
    }
    __syncthreads();

    // ---- pass 2: scatter senders into sorted LDS list ----
    for (int it = 0; it < REGSZ / 256; ++it) {
        const int i    = it * 256 + tid;
        const int cell = i / SUBCAP;
        const int q    = i - cell * SUBCAP;
        if (q < fills[cell]) {
            const unsigned e = bedges[s0 + i];
            const int p = atomicAdd(&cnt[(e >> 17) & (RCR - 1)], 1);
            if (p < CAPC) sortedL[p] = e & 0x1FFFF;
        }
    }
    __syncthreads();

    // ---- phase 2: proven agg loop (wave-per-receiver-PAIR, x2 unrolled) ----
    const int i8 = lane >> 3;   // edge sub-slot 0..7
    const int j  = lane & 7;    // channel group 0..7

    for (int t = w; t < nr; t += 8) {
        const int rlA = t;
        const int rlB = t + 4;
        const bool hasB = (rlB < nr);

        const int degA = rc[rlA];
        const int o0A  = rb[rlA];
        const int degB = hasB ? rc[rlB] : 0;
        const int o0B  = hasB ? rb[rlB] : o0A;

        const ushort4 qa = *(const ushort4*)((const ushort*)sQ + rlA * DIM + j * 4);
        const ushort4 qb = *(const ushort4*)((const ushort*)sQ + (rlB & (RCR - 1)) * DIM + j * 4);
        const float qA0 = h2f(qa.x), qA1 = h2f(qa.y), qA2 = h2f(qa.z), qA3 = h2f(qa.w);
        const float qB0 = h2f(qb.x), qB1 = h2f(qb.y), qB2 = h2f(qb.z), qB3 = h2f(qb.w);

        float axA = 0.f, ayA = 0.f, azA = 0.f, awA = 0.f, zsA = 0.f;
        float axB = 0.f, ayB = 0.f, azB = 0.f, awB = 0.f, zsB = 0.f;

        const int chA = (degA + 7) >> 3;
        const int chB = (degB + 7) >> 3;
        const int cmax = max(chA, chB);
        const int dmA = max(degA - 1, 0);
        const int dmB = max(degB - 1, 0);

        for (int cc = 0; cc < cmax; cc += 2) {
            const int c0 = cc * 8 + i8;
            const int c1 = c0 + 8;
            const bool okA0 = (c0 < degA), okA1 = (c1 < degA);
            const bool okB0 = (c0 < degB), okB1 = (c1 < degB);

            const int sA0 = min((int)sortedL[min(o0A + (okA0 ? c0 : dmA), CAPC - 1)], N - 1);
            const int sA1 = min((int)sortedL[min(o0A + (okA1 ? c1 : dmA), CAPC - 1)], N - 1);
            const int sB0 = min((int)sortedL[min(o0B + (okB0 ? c0 : dmB), CAPC - 1)], N - 1);
            const int sB1 = min((int)sortedL[min(o0B + (okB1 ? c1 : dmB), CAPC - 1)], N - 1);

            const ushort* pA0 = KV + (size_t)sA0 * 64;
            const ushort* pA1 = KV + (size_t)sA1 * 64;
            const ushort* pB0 = KV + (size_t)sB0 * 64;
            const ushort* pB1 = KV + (size_t)sB1 * 64;

            // issue all 8 loads before any consumption
            const ushort4 khA0 = *(const ushort4*)(pA0 + j * 4);
            const ushort4 vhA0 = *(const ushort4*)(pA0 + 32 + j * 4);
            const ushort4 khA1 = *(const ushort4*)(pA1 + j * 4);
            const ushort4 vhA1 = *(const ushort4*)(pA1 + 32 + j * 4);
            const ushort4 khB0 = *(const ushort4*)(pB0 + j * 4);
            const ushort4 vhB0 = *(const ushort4*)(pB0 + 32 + j * 4);
            const ushort4 khB1 = *(const ushort4*)(pB1 + j * 4);
            const ushort4 vhB1 = *(const ushort4*)(pB1 + 32 + j * 4);

            float pA = h2f(khA0.x) * qA0;
            float pAx = h2f(khA1.x) * qA0;
            float pB = h2f(khB0.x) * qB0;
            float pBx = h2f(khB1.x) * qB0;
            pA  = fmaf(h2f(khA0.y), qA1, pA);   pAx = fmaf(h2f(khA1.y), qA1, pAx);
            pB  = fmaf(h2f(khB0.y), qB1, pB);   pBx = fmaf(h2f(khB1.y), qB1, pBx);
            pA  = fmaf(h2f(khA0.z), qA2, pA);   pAx = fmaf(h2f(khA1.z), qA2, pAx);
            pB  = fmaf(h2f(khB0.z), qB2, pB);   pBx = fmaf(h2f(khB1.z), qB2, pBx);
            pA  = fmaf(h2f(khA0.w), qA3, pA);   pAx = fmaf(h2f(khA1.w), qA3, pAx);
            pB  = fmaf(h2f(khB0.w), qB3, pB);   pBx = fmaf(h2f(khB1.w), qB3, pBx);

            pA  += __shfl_xor(pA, 1);   pAx += __shfl_xor(pAx, 1);
            pB  += __shfl_xor(pB, 1);   pBx += __shfl_xor(pBx, 1);
            pA  += __shfl_xor(pA, 2);   pAx += __shfl_xor(pAx, 2);
            pB  += __shfl_xor(pB, 2);   pBx += __shfl_xor(pBx, 2);
            pA  += __shfl_xor(pA, 4);   pAx += __shfl_xor(pAx, 4);
            pB  += __shfl_xor(pB, 4);   pBx += __shfl_xor(pBx, 4);

            pA  = fminf(fmaxf(pA,  -60.f), 60.f);
            pAx = fminf(fmaxf(pAx, -60.f), 60.f);
            pB  = fminf(fmaxf(pB,  -60.f), 60.f);
            pBx = fminf(fmaxf(pBx, -60.f), 60.f);
            const float aA0 = okA0 ? __expf(pA)  : 0.f;
            const float aA1 = okA1 ? __expf(pAx) : 0.f;
            const float aB0 = okB0 ? __expf(pB)  : 0.f;
            const float aB1 = okB1 ? __expf(pBx) : 0.f;

            axA = fmaf(h2f(vhA0.x), aA0, axA);  axA = fmaf(h2f(vhA1.x), aA1, axA);
            ayA = fmaf(h2f(vhA0.y), aA0, ayA);  ayA = fmaf(h2f(vhA1.y), aA1, ayA);
            azA = fmaf(h2f(vhA0.z), aA0, azA);  azA = fmaf(h2f(vhA1.z), aA1, azA);
            awA = fmaf(h2f(vhA0.w), aA0, awA);  awA = fmaf(h2f(vhA1.w), aA1, awA);
            zsA += aA0 + aA1;

            axB = fmaf(h2f(vhB0.x), aB0, axB);  axB = fmaf(h2f(vhB1.x), aB1, axB);
            ayB = fmaf(h2f(vhB0.y), aB0, ayB);  ayB = fmaf(h2f(vhB1.y), aB1, ayB);
            azB = fmaf(h2f(vhB0.z), aB0, azB);  azB = fmaf(h2f(vhB1.z), aB1, azB);
            awB = fmaf(h2f(vhB0.w), aB0, awB);  awB = fmaf(h2f(vhB1.w), aB1, awB);
            zsB += aB0 + aB1;
        }

#pragma unroll
        for (int o = 8; o < 64; o <<= 1) {
            axA += __shfl_xor(axA, o); ayA += __shfl_xor(ayA, o);
            azA += __shfl_xor(azA, o); awA += __shfl_xor(awA, o);
            zsA += __shfl_xor(zsA, o);
            axB += __shfl_xor(axB, o); ayB += __shfl_xor(ayB, o);
            azB += __shfl_xor(azB, o); awB += __shfl_xor(awB, o);
            zsB += __shfl_xor(zsB, o);
        }
        if (i8 == 0) {
            float* arA = accS[rlA];
            arA[j * 4 + 0] = axA; arA[j * 4 + 1] = ayA;
            arA[j * 4 + 2] = azA; arA[j * 4 + 3] = awA;
            if (j == 0) arA[32] = zsA;
            if (hasB) {
                float* arB = accS[rlB];
                arB[j * 4 + 0] = axB; arB[j * 4 + 1] = ayB;
                arB[j * 4 + 2] = azB; arB[j * 4 + 3] = awB;
                if (j == 0) arB[32] = zsB;
            }
        }
    }
    __syncthreads();

    // ---- epilogue: out = x + (acc/Z) @ Wo ----
    const int d = tid & 31;
    for (int r = tid >> 5; r < nr; r += 8) {
        const float inv = 1.f / (accS[r][32] + 1e-6f);
        float o = 0.f;
#pragma unroll
        for (int k = 0; k < DIM; ++k) o += accS[r][k] * sWo[k * DIM + d];
        const size_t oi = (size_t)(r0 + r) * DIM + d;
        out[oi] = load_f(x_, oi, bf) + inv * o;
    }
}

// ---------------------------------------------------------------------------
extern "C" void kernel_launch(void* const* d_in, const int* in_sizes, int n_in,
                              void* d_out, int out_size, void* d_ws, size_t ws_size,
                              hipStream_t stream) {
    const void* x   = d_in[0];
    const int*  idx = (const int*)d_in[1];
    const void* Wq  = d_in[2];
    const void* Wk  = d_in[3];
    const void* Wv  = d_in[4];
    const void* Wo  = d_in[5];
    float* out = (float*)d_out;           // fp32 reference output

    const int N = in_sizes[0] / DIM;      // 100000
    const int E = in_sizes[1] / 2;        // 1600000
    const int nc = (N + RCR - 1) / RCR;   // 782 regions
    const size_t N32 = (size_t)N * DIM;

    // Workspace (~38.8 MB): Q f16 | KV f16 | bedges cells | hcnt
    ushort*   Q      = (ushort*)d_ws;
    ushort*   KV     = Q + N32;                              // N * 64 halves
    unsigned* bedges = (unsigned*)(KV + (size_t)N * 64);     // nc * REGSZ
    int*      hcnt   = (int*)(bedges + (size_t)nc * REGSZ);  // nc * PBLK

    const int gemm_blocks = (N + 31) / 32;   // 3125
    qkv_place_kernel<<<PBLK + gemm_blocks, 256, 0, stream>>>(
        x, idx, Wq, Wk, Wv, N, E, nc, Q, KV, bedges, hcnt);

    sortagg_kernel<<<nc, 256, 0, stream>>>(Q, KV, bedges, hcnt, x, Wo, N, out);
}

// Round 7
// 177.129 us; speedup vs baseline: 1.3935x; 1.2378x over previous
//
#include <hip/hip_runtime.h>

#define DIM 32
#define RCR 256             // receivers per region -> nc = 391 at N=100K
#define NCMAX 1024          // max regions supported
#define PBLK 256            // place blocks (one cell per (region, place-block))
#define SUBCAP 48           // cap per cell; lambda=16 (+8 sigma)
#define REGSZ (PBLK * SUBCAP)   // 12288 slots per region
#define CAPC 5248           // rsort LDS stage cap; region lambda 4096, +18 sigma

// ---------------- f16 / bf16 <-> fp32 helpers ------------------------------
__device__ __forceinline__ float b2f(ushort h) {
    union { float f; unsigned u; } u; u.u = ((unsigned)h) << 16; return u.f;
}
__device__ __forceinline__ float h2f(ushort u) {
    _Float16 h; __builtin_memcpy(&h, &u, 2); return (float)h;
}
__device__ __forceinline__ ushort f2h(float f) {
    _Float16 h = (_Float16)f; ushort u; __builtin_memcpy(&u, &h, 2); return u;
}
__device__ __forceinline__ int clampN(int v, int n) {
    return v < 0 ? 0 : (v >= n ? n - 1 : v);
}
__device__ __forceinline__ int load_idx(const int* __restrict__ idx, size_t pos,
                                        int mode, int n) {
    int v = mode ? idx[2 * pos] : idx[pos];
    return clampN(v, n);
}
__device__ __forceinline__ float load_f(const void* p, size_t i, int bf) {
    return bf ? b2f(((const ushort*)p)[i]) : ((const float*)p)[i];
}

// packed f16x2 dot -> f32 (v_dot2_f32_f16); guarded fallback = scalar path
typedef _Float16 half2v __attribute__((ext_vector_type(2)));
__device__ __forceinline__ float dot2(unsigned a, unsigned b, float c) {
#if __has_builtin(__builtin_amdgcn_fdot2)
    half2v ha, hb;
    __builtin_memcpy(&ha, &a, 4); __builtin_memcpy(&hb, &b, 4);
    return __builtin_amdgcn_fdot2(ha, hb, c, false);
#else
    return fmaf(h2f((ushort)(a >> 16)), h2f((ushort)(b >> 16)),
                fmaf(h2f((ushort)a), h2f((ushort)b), c));
#endif
}

// GEMM smem and place histogram share the block's LDS (union).
union K1Smem {
    struct { float sW[3][DIM * DIM]; float sx[32][36]; } g;   // 16.6 KB
    struct { int h[NCMAX]; } place;                           //  4 KB
};

// ---------------------------------------------------------------------------
// K1: blocks [0,PBLK) = cell-structured place, now 256 blocks (R4's 128
// ran the place tail on half the chip -> occupancy 24%). Block-private
// cells -> dense single-XCD write lines (R2: alternative = 120 MB writes).
// blocks [PBLK,..) = QKV GEMM, 32 rows/block, 1 row/thread (VGPR 48
// proven; the 4-row variant spilled at VGPR 256 in R5).
// ---------------------------------------------------------------------------
__global__ void __launch_bounds__(256)
qkv_place_kernel(const void* __restrict__ x_, const int* __restrict__ idx,
                 const void* __restrict__ Wq_, const void* __restrict__ Wk_,
                 const void* __restrict__ Wv_, int N, int E, int nc,
                 ushort* __restrict__ Q, ushort* __restrict__ KV,
                 unsigned* __restrict__ bedges, int* __restrict__ hcnt) {
    __shared__ K1Smem sm;
    __shared__ int sBf, sMode;

    const int tid = threadIdx.x;
    if (tid < 64) {
        int e = (((const ushort*)x_)[2 * tid] >> 7) & 0xFF;
        unsigned long long bb = __ballot(e >= 100 && e <= 135);
        unsigned long long mm = __ballot(idx[2 * tid + 1] != 0);
        if (tid == 0) { sBf = (__popcll(bb) >= 56); sMode = (mm == 0ULL); }
    }
    __syncthreads();
    const int bf = sBf, mode = sMode;

    if (blockIdx.x < PBLK) {
        // ---- place: append edge (s | r_local<<17) into cell (region, pb) ----
        const int pb = blockIdx.x;
        for (int i = tid; i < nc; i += 256) sm.place.h[i] = 0;
        __syncthreads();
        const int per = (E + PBLK - 1) / PBLK;
        const int e0 = pb * per;
        const int e1 = min(e0 + per, E);
        for (int e = e0 + tid; e < e1; e += 256) {
            const int r = load_idx(idx, (size_t)E + e, mode, N);
            const int s = load_idx(idx, (size_t)e, mode, N);
            const int reg = r >> 8;               // r / RCR
            const int rl  = r & (RCR - 1);
            const int p = atomicAdd(&sm.place.h[reg], 1);
            if (p < SUBCAP)
                bedges[(size_t)reg * REGSZ + pb * SUBCAP + p] =
                    (unsigned)s | ((unsigned)rl << 17);
        }
        __syncthreads();
        for (int i = tid; i < nc; i += 256)
            hcnt[i * PBLK + pb] = min(sm.place.h[i], SUBCAP);
        return;
    }

    // ---- QKV GEMM: 32 rows/block, thread = (row, 4 contiguous cols) ----
    for (int i = tid; i < DIM * DIM; i += 256) {
        sm.g.sW[0][i] = load_f(Wq_, i, bf);
        sm.g.sW[1][i] = load_f(Wk_, i, bf);
        sm.g.sW[2][i] = load_f(Wv_, i, bf);
    }
    const int base = (blockIdx.x - PBLK) * 32;
    for (int i = tid; i < 32 * 8; i += 256) {      // 8 float4-chunks per row
        const int r  = i >> 3;
        const int c4 = (i & 7) << 2;
        const int row = base + r;
        float4 v; v.x = v.y = v.z = v.w = 0.f;
        if (row < N) {
            if (!bf) {
                v = *(const float4*)((const float*)x_ + (size_t)row * DIM + c4);
            } else {
                const ushort4 u =
                    *(const ushort4*)((const ushort*)x_ + (size_t)row * DIM + c4);
                v.x = b2f(u.x); v.y = b2f(u.y); v.z = b2f(u.z); v.w = b2f(u.w);
            }
        }
        *(float4*)&sm.g.sx[r][c4] = v;
    }
    __syncthreads();

    const int lr  = tid >> 3;          // row 0..31
    const int d4  = (tid & 7) << 2;    // 4-col group
    const int row = base + lr;
    if (row >= N) return;

    float aq[4] = {0.f, 0.f, 0.f, 0.f};
    float ak[4] = {0.f, 0.f, 0.f, 0.f};
    float av[4] = {0.f, 0.f, 0.f, 0.f};
#pragma unroll
    for (int k0 = 0; k0 < DIM; k0 += 4) {
        const float4 xq = *(const float4*)&sm.g.sx[lr][k0];
        const float xs[4] = {xq.x, xq.y, xq.z, xq.w};
#pragma unroll
        for (int kk = 0; kk < 4; ++kk) {
            const float xv = xs[kk];
            const float4 wq = *(const float4*)&sm.g.sW[0][(k0 + kk) * DIM + d4];
            const float4 wk = *(const float4*)&sm.g.sW[1][(k0 + kk) * DIM + d4];
            const float4 wv = *(const float4*)&sm.g.sW[2][(k0 + kk) * DIM + d4];
            aq[0] = fmaf(xv, wq.x, aq[0]); aq[1] = fmaf(xv, wq.y, aq[1]);
            aq[2] = fmaf(xv, wq.z, aq[2]); aq[3] = fmaf(xv, wq.w, aq[3]);
            ak[0] = fmaf(xv, wk.x, ak[0]); ak[1] = fmaf(xv, wk.y, ak[1]);
            ak[2] = fmaf(xv, wk.z, ak[2]); ak[3] = fmaf(xv, wk.w, ak[3]);
            av[0] = fmaf(xv, wv.x, av[0]); av[1] = fmaf(xv, wv.y, av[1]);
            av[2] = fmaf(xv, wv.z, av[2]); av[3] = fmaf(xv, wv.w, av[3]);
        }
    }
    const float sc = 0.17677669529663687f;   // 1/sqrt(32), pre-scale Q
    ushort4 t;
    t.x = f2h(aq[0] * sc); t.y = f2h(aq[1] * sc);
    t.z = f2h(aq[2] * sc); t.w = f2h(aq[3] * sc);
    *(ushort4*)&Q[(size_t)row * DIM + d4] = t;
    t.x = f2h(ak[0]); t.y = f2h(ak[1]); t.z = f2h(ak[2]); t.w = f2h(ak[3]);
    *(ushort4*)&KV[(size_t)row * 64 + d4] = t;
    t.x = f2h(av[0]); t.y = f2h(av[1]); t.z = f2h(av[2]); t.w = f2h(av[3]);
    *(ushort4*)&KV[(size_t)row * 64 + 32 + d4] = t;
}

// ---------------------------------------------------------------------------
// K2 (rsort): one 512-thread block per region of RCR=256 receivers (391
// blocks, ~4 co-resident/CU at 24 KB LDS). Staging now reads slots as
// uint4 (4 slots/thread/iter, 6 iterations vs 24 scalar) -- the old loop
// issued one latency-chained scalar load per slot, 70% of them invalid.
// Then counting-sort by r_local, dense in-place write-back + CSR.
// ---------------------------------------------------------------------------
__global__ void __launch_bounds__(512)
rsort_kernel(unsigned* __restrict__ bedges, const int* __restrict__ hcnt,
             int* __restrict__ rbase, int* __restrict__ rcount, int N) {
    __shared__ unsigned eL[CAPC];     // 21 KB
    __shared__ int cnt[RCR];
    __shared__ int fills[PBLK];
    __shared__ int cbase[PBLK];
    __shared__ int wsum[4];

    const int tid = threadIdx.x;
    const int c = blockIdx.x;
    const size_t s0 = (size_t)c * REGSZ;
    const int lane = tid & 63, w = tid >> 6;

    if (tid < RCR) cnt[tid] = 0;
    if (tid < PBLK) fills[tid] = hcnt[c * PBLK + tid];
    __syncthreads();

    // exclusive prefix over fills[0..255] -> cbase (4-wave shfl scan)
    int fv = 0, fx = 0;
    if (tid < PBLK) {
        fv = fills[tid]; fx = fv;
#pragma unroll
        for (int o = 1; o < 64; o <<= 1) {
            int t = __shfl_up(fx, o); if (lane >= o) fx += t;
        }
        if (lane == 63) wsum[w] = fx;
    }
    __syncthreads();
    if (tid == 0) {
        int a = 0;
#pragma unroll
        for (int k = 0; k < 4; ++k) { int t = wsum[k]; wsum[k] = a; a += t; }
    }
    __syncthreads();
    if (tid < PBLK) cbase[tid] = fx - fv + wsum[w];
    __syncthreads();
    const int nTot = cbase[PBLK - 1] + fills[PBLK - 1];

    // ---- staging: uint4 slot loads, fill-gated; histogram by r_local ----
    for (int j = tid; j < REGSZ / 4; j += 512) {
        const int cell = j / (SUBCAP / 4);                 // SUBCAP/4 = 12
        const int q0   = (j - cell * (SUBCAP / 4)) * 4;
        const int fc   = fills[cell];
        if (q0 < fc) {
            const uint4 e4 = *(const uint4*)&bedges[s0 + (size_t)j * 4];
            const int base = cbase[cell] + q0;
            if (base < CAPC) {
                eL[base] = e4.x;
                atomicAdd(&cnt[(e4.x >> 17) & (RCR - 1)], 1);
            }
            if (q0 + 1 < fc && base + 1 < CAPC) {
                eL[base + 1] = e4.y;
                atomicAdd(&cnt[(e4.y >> 17) & (RCR - 1)], 1);
            }
            if (q0 + 2 < fc && base + 2 < CAPC) {
                eL[base + 2] = e4.z;
                atomicAdd(&cnt[(e4.z >> 17) & (RCR - 1)], 1);
            }
            if (q0 + 3 < fc && base + 3 < CAPC) {
                eL[base + 3] = e4.w;
                atomicAdd(&cnt[(e4.w >> 17) & (RCR - 1)], 1);
            }
        }
    }
    __syncthreads();

    // exclusive prefix over cnt[0..255] -> per-receiver CSR
    const int v = (tid < RCR) ? cnt[tid] : 0;
    int x = v;
    if (tid < RCR) {
#pragma unroll
        for (int o = 1; o < 64; o <<= 1) {
            int t = __shfl_up(x, o); if (lane >= o) x += t;
        }
        if (lane == 63) wsum[w] = x;
    }
    __syncthreads();
    if (tid == 0) {
        int a = 0;
#pragma unroll
        for (int k = 0; k < 4; ++k) { int t = wsum[k]; wsum[k] = a; a += t; }
    }
    __syncthreads();
    int excl = 0;
    if (tid < RCR) {
        excl = x - v + wsum[w];
        rbase[c * RCR + tid]  = (int)s0 + excl;
        rcount[c * RCR + tid] = v;
    }
    __syncthreads();
    if (tid < RCR) cnt[tid] = excl;     // region-relative scatter cursor
    __syncthreads();

    const int m = min(nTot, CAPC);
    for (int i = tid; i < m; i += 512) {
        const unsigned e = eL[i];
        const int p = atomicAdd(&cnt[(e >> 17) & (RCR - 1)], 1);
        bedges[s0 + p] = e & 0x1FFFF;
    }
}

// ---------------------------------------------------------------------------
// K3 (agg): proven structure (wave-per-receiver-PAIR, register accumulation,
// shfl reduce, fused normalize + @Wo + residual); QK dot now via
// v_dot2_f32_f16 (dot2 helper) -- replaces 16 h2f + 16 fma per iteration
// with 8 dot2. V path unchanged (h2f+fma, mad_mix-fusable).
// ---------------------------------------------------------------------------
__global__ void __launch_bounds__(256)
agg_kernel(const ushort* __restrict__ Q, const ushort* __restrict__ KV,
           const unsigned* __restrict__ bedges, const int* __restrict__ rbase,
           const int* __restrict__ rcount, const void* __restrict__ x_,
           const void* __restrict__ Wo_, int N, float* __restrict__ out) {
    __shared__ float sWo[DIM * DIM];
    __shared__ float accS[32][DIM + 1];
    __shared__ float Zs[32];
    __shared__ unsigned sQ[32 * 16];
    __shared__ int sBf;

    const int tid = threadIdx.x;
    if (tid < 64) {
        int e = (((const ushort*)x_)[2 * tid] >> 7) & 0xFF;
        unsigned long long bb = __ballot(e >= 100 && e <= 135);
        if (tid == 0) sBf = (__popcll(bb) >= 56);
    }
    const int r0 = blockIdx.x * 32;
    const int nr = min(32, N - r0);
    __syncthreads();
    const int bf = sBf;

    for (int i = tid; i < DIM * DIM; i += 256) sWo[i] = load_f(Wo_, i, bf);
    for (int i = tid; i < nr * 16; i += 256)
        sQ[i] = ((const unsigned*)(Q + (size_t)r0 * DIM))[i];
    __syncthreads();

    const int w    = tid >> 6;
    const int lane = tid & 63;
    const int i8   = lane >> 3;   // edge sub-slot 0..7
    const int j    = lane & 7;    // channel group 0..7

    for (int t = w; t < nr; t += 8) {
        const int rlA = t;
        const int rlB = t + 4;
        const bool hasB = (rlB < nr);

        const int degA = rcount[r0 + rlA];
        const int o0A  = rbase[r0 + rlA];
        const int degB = hasB ? rcount[r0 + rlB] : 0;
        const int o0B  = hasB ? rbase[r0 + rlB] : o0A;

        // Q as packed f16x2 words (channels 4j..4j+3 = words 2j, 2j+1)
        const unsigned qA01 = sQ[rlA * 16 + j * 2];
        const unsigned qA23 = sQ[rlA * 16 + j * 2 + 1];
        const unsigned qB01 = sQ[(rlB & 31) * 16 + j * 2];
        const unsigned qB23 = sQ[(rlB & 31) * 16 + j * 2 + 1];

        float axA = 0.f, ayA = 0.f, azA = 0.f, awA = 0.f, zsA = 0.f;
        float axB = 0.f, ayB = 0.f, azB = 0.f, awB = 0.f, zsB = 0.f;

        const int chA = (degA + 7) >> 3;
        const int chB = (degB + 7) >> 3;
        const int cmax = max(chA, chB);
        const int dmA = max(degA - 1, 0);
        const int dmB = max(degB - 1, 0);

        for (int cc = 0; cc < cmax; cc += 2) {
            const int c0 = cc * 8 + i8;
            const int c1 = c0 + 8;
            const bool okA0 = (c0 < degA), okA1 = (c1 < degA);
            const bool okB0 = (c0 < degB), okB1 = (c1 < degB);

            const int sA0 = (int)bedges[o0A + (okA0 ? c0 : dmA)];
            const int sA1 = (int)bedges[o0A + (okA1 ? c1 : dmA)];
            const int sB0 = (int)bedges[o0B + (okB0 ? c0 : dmB)];
            const int sB1 = (int)bedges[o0B + (okB1 ? c1 : dmB)];

            const ushort* pA0 = KV + (size_t)sA0 * 64;
            const ushort* pA1 = KV + (size_t)sA1 * 64;
            const ushort* pB0 = KV + (size_t)sB0 * 64;
            const ushort* pB1 = KV + (size_t)sB1 * 64;

            // issue all 8 loads before any consumption (packed f16x2 words)
            const uint2 kA0 = *(const uint2*)(pA0 + j * 4);
            const uint2 vA0 = *(const uint2*)(pA0 + 32 + j * 4);
            const uint2 kA1 = *(const uint2*)(pA1 + j * 4);
            const uint2 vA1 = *(const uint2*)(pA1 + 32 + j * 4);
            const uint2 kB0 = *(const uint2*)(pB0 + j * 4);
            const uint2 vB0 = *(const uint2*)(pB0 + 32 + j * 4);
            const uint2 kB1 = *(const uint2*)(pB1 + j * 4);
            const uint2 vB1 = *(const uint2*)(pB1 + 32 + j * 4);

            float pA  = dot2(kA0.y, qA23, dot2(kA0.x, qA01, 0.f));
            float pAx = dot2(kA1.y, qA23, dot2(kA1.x, qA01, 0.f));
            float pB  = dot2(kB0.y, qB23, dot2(kB0.x, qB01, 0.f));
            float pBx = dot2(kB1.y, qB23, dot2(kB1.x, qB01, 0.f));

            pA  += __shfl_xor(pA, 1);   pAx += __shfl_xor(pAx, 1);
            pB  += __shfl_xor(pB, 1);   pBx += __shfl_xor(pBx, 1);
            pA  += __shfl_xor(pA, 2);   pAx += __shfl_xor(pAx, 2);
            pB  += __shfl_xor(pB, 2);   pBx += __shfl_xor(pBx, 2);
            pA  += __shfl_xor(pA, 4);   pAx += __shfl_xor(pAx, 4);
            pB  += __shfl_xor(pB, 4);   pBx += __shfl_xor(pBx, 4);

            pA  = fminf(fmaxf(pA,  -60.f), 60.f);
            pAx = fminf(fmaxf(pAx, -60.f), 60.f);
            pB  = fminf(fmaxf(pB,  -60.f), 60.f);
            pBx = fminf(fmaxf(pBx, -60.f), 60.f);
            const float aA0 = okA0 ? __expf(pA)  : 0.f;
            const float aA1 = okA1 ? __expf(pAx) : 0.f;
            const float aB0 = okB0 ? __expf(pB)  : 0.f;
            const float aB1 = okB1 ? __expf(pBx) : 0.f;

            axA = fmaf(h2f((ushort)vA0.x), aA0, axA);
            ayA = fmaf(h2f((ushort)(vA0.x >> 16)), aA0, ayA);
            azA = fmaf(h2f((ushort)vA0.y), aA0, azA);
            awA = fmaf(h2f((ushort)(vA0.y >> 16)), aA0, awA);
            axA = fmaf(h2f((ushort)vA1.x), aA1, axA);
            ayA = fmaf(h2f((ushort)(vA1.x >> 16)), aA1, ayA);
            azA = fmaf(h2f((ushort)vA1.y), aA1, azA);
            awA = fmaf(h2f((ushort)(vA1.y >> 16)), aA1, awA);
            zsA += aA0 + aA1;

            axB = fmaf(h2f((ushort)vB0.x), aB0, axB);
            ayB = fmaf(h2f((ushort)(vB0.x >> 16)), aB0, ayB);
            azB = fmaf(h2f((ushort)vB0.y), aB0, azB);
            awB = fmaf(h2f((ushort)(vB0.y >> 16)), aB0, awB);
            axB = fmaf(h2f((ushort)vB1.x), aB1, axB);
            ayB = fmaf(h2f((ushort)(vB1.x >> 16)), aB1, ayB);
            azB = fmaf(h2f((ushort)vB1.y), aB1, azB);
            awB = fmaf(h2f((ushort)(vB1.y >> 16)), aB1, awB);
            zsB += aB0 + aB1;
        }

#pragma unroll
        for (int o = 8; o < 64; o <<= 1) {
            axA += __shfl_xor(axA, o); ayA += __shfl_xor(ayA, o);
            azA += __shfl_xor(azA, o); awA += __shfl_xor(awA, o);
            zsA += __shfl_xor(zsA, o);
            axB += __shfl_xor(axB, o); ayB += __shfl_xor(ayB, o);
            azB += __shfl_xor(azB, o); awB += __shfl_xor(awB, o);
            zsB += __shfl_xor(zsB, o);
        }
        if (i8 == 0) {
            float* arA = accS[rlA];
            arA[j * 4 + 0] = axA; arA[j * 4 + 1] = ayA;
            arA[j * 4 + 2] = azA; arA[j * 4 + 3] = awA;
            if (j == 0) Zs[rlA] = zsA;
            if (hasB) {
                float* arB = accS[rlB];
                arB[j * 4 + 0] = axB; arB[j * 4 + 1] = ayB;
                arB[j * 4 + 2] = azB; arB[j * 4 + 3] = awB;
                if (j == 0) Zs[rlB] = zsB;
            }
        }
    }
    __syncthreads();

    const int lr = tid >> 5;
    const int d  = tid & 31;
#pragma unroll
    for (int it = 0; it < 4; ++it) {
        const int rl = it * 8 + lr;
        if (rl < nr) {
            const float inv = 1.f / (Zs[rl] + 1e-6f);
            float o = 0.f;
#pragma unroll
            for (int k = 0; k < DIM; ++k) o += accS[rl][k] * sWo[k * DIM + d];
            const size_t oi = (size_t)(r0 + rl) * DIM + d;
            out[oi] = load_f(x_, oi, bf) + inv * o;
        }
    }
}

// ---------------------------------------------------------------------------
extern "C" void kernel_launch(void* const* d_in, const int* in_sizes, int n_in,
                              void* d_out, int out_size, void* d_ws, size_t ws_size,
                              hipStream_t stream) {
    const void* x   = d_in[0];
    const int*  idx = (const int*)d_in[1];
    const void* Wq  = d_in[2];
    const void* Wk  = d_in[3];
    const void* Wv  = d_in[4];
    const void* Wo  = d_in[5];
    float* out = (float*)d_out;           // fp32 reference output

    const int N = in_sizes[0] / DIM;      // 100000
    const int E = in_sizes[1] / 2;        // 1600000
    const int nc = (N + RCR - 1) / RCR;   // 391 regions
    const size_t N32 = (size_t)N * DIM;

    // Workspace (~39.6 MB): Q f16 | KV f16 | bedges cells | hcnt | rbase | rcount
    ushort*   Q      = (ushort*)d_ws;
    ushort*   KV     = Q + N32;                              // N * 64 halves
    unsigned* bedges = (unsigned*)(KV + (size_t)N * 64);     // nc * REGSZ
    int*      hcnt   = (int*)(bedges + (size_t)nc * REGSZ);  // nc * PBLK
    int*      rbase  = hcnt + (size_t)nc * PBLK;             // nc * RCR
    int*      rcount = rbase + (size_t)nc * RCR;             // nc * RCR

    const int gemm_blocks = (N + 31) / 32;   // 3125
    qkv_place_kernel<<<PBLK + gemm_blocks, 256, 0, stream>>>(
        x, idx, Wq, Wk, Wv, N, E, nc, Q, KV, bedges, hcnt);

    rsort_kernel<<<nc, 512, 0, stream>>>(bedges, hcnt, rbase, rcount, N);

    agg_kernel<<<(N + 31) / 32, 256, 0, stream>>>(Q, KV, bedges, rbase,
                                                  rcount, x, Wo, N, out);
}